// Round 7
// baseline (540.207 us; speedup 1.0000x reference)
//
#include <hip/hip_runtime.h>

// ConvLSTM B=8,T=16,CIN=16,HID=64,H=W=64,K=3 'SAME' — 16-launch bf16 MFMA.
// R6 lesson: halving B-frag L2 traffic regressed -> not BW-bound; step time
// tracks concurrent waves -> latency-bound on the serial per-block phase chain.
// R7: R5 shape (M=32, 1024 blocks) but 512-thread blocks with SPLIT-K:
// waves 0-3 do kt 0..12, waves 4-7 do kt 13..26 on the same tile; partials
// combined via 32KB LDS reduce (reuses Xs region after K-loop). Staging and
// zeroing run with 2x threads; serial K-chain per wave halves; traffic const.

#define B_ 8
#define T_ 16
#define CIN_ 16
#define HID_ 64
#define H_ 64
#define W_ 64
#define HW_ (H_*W_)
#define CTOT_ 80
#define XS_ROW 34                 // 32 px + 2 halo
#define XS_CH 104                 // 96 K-ch + bias + pad; 52-word stride -> 2-way banks (free)
#define XS_SIZE (3*XS_ROW*XS_CH)  // 10608 hw = 21216 B
#define SM_BYTES 32768            // max(Xs 21216, P 32768)
#define KSPLIT 13                 // waves 0-3: kt<13 (+epilogue), waves 4-7: kt>=13
#define CSTRIDE_ (B_*HID_*HW_)    // 2097152

typedef __attribute__((ext_vector_type(8))) short short8;
typedef __attribute__((ext_vector_type(4))) float f32x4;

__device__ __forceinline__ unsigned short f2bf(float f){
    unsigned u = __float_as_uint(f);
    u = (u + 0x7FFFu + ((u >> 16) & 1u)) >> 16;   // RNE
    return (unsigned short)u;
}
__device__ __forceinline__ float sigm_(float v){ return 1.0f/(1.0f + __expf(-v)); }
__device__ __forceinline__ float tanh_(float v){ return 2.0f/(1.0f + __expf(-2.0f*v)) - 1.0f; }

// Wfrag: [tap 9][cc 3][ng 16] frags of 512 hw ([lane][j]).
// n = ng*16+(lane&15): g=n>>6, o=n&63; k-ch c = cc*32+(lane>>4)*8+j.
// Bias folded at c==80 (constant-1 A channel), center tap only.
__global__ void prep_wfrag(const float* __restrict__ Wf, const float* __restrict__ Wi,
                           const float* __restrict__ Wc, const float* __restrict__ Wo,
                           const float* __restrict__ bf, const float* __restrict__ bi,
                           const float* __restrict__ bc, const float* __restrict__ bo,
                           unsigned short* __restrict__ Wfrag){
    int idx = blockIdx.x*256 + threadIdx.x;          // 864*256 = 221184 exact
    int j    = idx & 7;
    int lane = (idx >> 3) & 63;
    int frag = idx >> 9;
    int ng = frag & 15;
    int tc = frag >> 4;
    int cc = tc % 3, tap = tc / 3;
    int n = ng*16 + (lane & 15);
    int g = n >> 6, o = n & 63;
    int c = cc*32 + ((lane >> 4) << 3) + j;
    int ky = tap / 3, kx = tap % 3;
    float v = 0.0f;
    if (c < CTOT_){
        if (g == 0)      v = Wf[((o*CTOT_ + c)*3 + ky)*3 + kx];
        else if (g == 1) v = Wi[((o*CTOT_ + c)*3 + ky)*3 + kx];
        else if (g == 2) v = Wc[((o*CTOT_ + c)*3 + ky)*3 + kx];
        else             v = (tap == 4) ? Wo[o*CTOT_ + c] : 0.0f;
    } else if (c == CTOT_ && tap == 4){              // bias channel
        v = (g==0) ? bf[o] : (g==1) ? bi[o] : (g==2) ? bc[o] : bo[o];
    }
    Wfrag[idx] = f2bf(v);
}

// x[b][t][c][y][px] fp32 -> xbf[b][t][y][px][c16] bf16
__global__ void prep_xbf(const float* __restrict__ x, unsigned short* __restrict__ xbf){
    int idx = blockIdx.x*256 + threadIdx.x;          // 524288 = (b,t,y,px) flat
    int px = idx & 63;
    int y  = (idx >> 6) & 63;
    int bt = idx >> 12;
    const float* src = x + (size_t)bt*CIN_*HW_ + y*W_ + px;
    unsigned short tmp[16];
    #pragma unroll
    for (int c = 0; c < 16; ++c) tmp[c] = f2bf(src[(size_t)c*HW_]);
    uint4* dst = (uint4*)(xbf + (size_t)idx*16);
    dst[0] = *(uint4*)(tmp);
    dst[1] = *(uint4*)(tmp + 8);
}

__global__ __launch_bounds__(512, 4) void lstm_step(
    const unsigned short* __restrict__ xbf,
    const unsigned short* __restrict__ Wfrag,
    float* __restrict__ cbuf,                        // [b][y][px][o] fp32, in place
    const unsigned short* __restrict__ hin,          // [b][y][px][o] bf16
    unsigned short* __restrict__ hout,
    float* __restrict__ out,                         // [h|c] std layout, t==15 only
    int t)
{
    __shared__ __align__(16) char smem[SM_BYTES];
    unsigned short* Xs = (unsigned short*)smem;
    float*          P  = (float*)smem;               // partial accs, used after Xs dead

    const int id   = blockIdx.x;
    // XCD swizzle: id&7 -> XCD; contiguous 8-row y band per XCD for halo locality.
    const int xcd  = id & 7;
    const int jj   = id >> 3;
    const int y    = xcd*8 + (jj & 7);
    const int b    = (jj >> 3) & 7;
    const int x0   = (jj >> 6) * 32;
    const int tid  = threadIdx.x;
    const int lane = tid & 63;
    const int w    = tid >> 6;                       // 0..7
    const int wl   = w & 3;                          // ng slice (o range)
    const int wh   = w >> 2;                         // K-half
    const int l15  = lane & 15;
    const int q    = lane >> 4;

    // ---- zero LDS (SAME-pad borders, pad channels)
    uint4 z4; z4.x=z4.y=z4.z=z4.w=0u;
    for (int i = tid; i < XS_SIZE/8; i += 512) ((uint4*)Xs)[i] = z4;
    __syncthreads();

    // ---- stage x: 3 rows x 34 px x 2 ch8 = 204 uint4
    for (int i = tid; i < 204; i += 512){
        int row = i/68, rem = i - row*68;
        int px = rem >> 1, ch8 = rem & 1;
        int yy = y + row - 1, pxg = x0 + px - 1;
        if (yy >= 0 && yy < H_ && pxg >= 0 && pxg < W_){
            uint4 v = *(const uint4*)(xbf + ((((size_t)(b*T_ + t)*H_ + yy)*W_ + pxg)*16 + ch8*8));
            *(uint4*)(Xs + (row*XS_ROW + px)*XS_CH + ch8*8) = v;
        }
    }
    // ---- stage h: 3 x 34 x 8 = 816 uint4 (t==0: stays zero)
    if (t > 0){
        for (int i = tid; i < 816; i += 512){
            int row = i/272, rem = i - row*272;
            int px = rem >> 3, ch8 = rem & 7;
            int yy = y + row - 1, pxg = x0 + px - 1;
            if (yy >= 0 && yy < H_ && pxg >= 0 && pxg < W_){
                uint4 v = *(const uint4*)(hin + ((((size_t)b*H_ + yy)*W_ + pxg)*HID_ + ch8*8));
                *(uint4*)(Xs + (row*XS_ROW + px)*XS_CH + CIN_ + ch8*8) = v;
            }
        }
    }
    // ---- constant-1 bias channel (ch 80)
    for (int i = tid; i < 3*XS_ROW; i += 512)
        Xs[i*XS_CH + CTOT_] = 0x3F80;                // bf16 1.0
    __syncthreads();

    // ---- split-K loop: this wave-half's kt range, one-ahead A/B prefetch
    f32x4 acc[4][2];
    #pragma unroll
    for (int g = 0; g < 4; ++g){ acc[g][0] = (f32x4)0.0f; acc[g][1] = (f32x4)0.0f; }

    const int ktot = t ? 27 : 9;                     // t==0: h==0, x chunk only
    int kbeg = wh ? KSPLIT : 0;
    int kend = wh ? ktot   : KSPLIT;
    if (kend > ktot) kend = ktot;
    if (kbeg > kend) kbeg = kend;                    // t==0 upper half: empty

    if (kbeg < kend){
        short8 aC[2], bC[3], bO;
        {   // preload kt = kbeg
            const int tap = kbeg % 9, cc = kbeg / 9;
            const int ky = tap/3, kx = tap%3;
            const unsigned short* ap = Xs + (size_t)(ky*XS_ROW + l15 + kx)*XS_CH + cc*32 + q*8;
            aC[0] = *(const short8*)ap;
            aC[1] = *(const short8*)(ap + 16*XS_CH);
            const unsigned short* bp = Wfrag + ((size_t)((tap*3 + cc)*16 + wl) << 9) + lane*8;
            #pragma unroll
            for (int g = 0; g < 3; ++g) bC[g] = *(const short8*)(bp + ((size_t)(g*4) << 9));
            if (tap == 4)
                bO = *(const short8*)(Wfrag + ((size_t)((4*3 + cc)*16 + 12 + wl) << 9) + lane*8);
        }
        for (int kt = kbeg; kt < kend; ++kt){
            const int tap = kt % 9;
            const int nk = kt + 1;
            const bool have = (nk < kend);
            short8 aN[2], bN[3], bOn;
            if (have){
                const int nt = nk % 9, nc = nk / 9;
                const int nky = nt/3, nkx = nt%3;
                const unsigned short* ap =
                    Xs + (size_t)(nky*XS_ROW + l15 + nkx)*XS_CH + nc*32 + q*8;
                aN[0] = *(const short8*)ap;
                aN[1] = *(const short8*)(ap + 16*XS_CH);
                const unsigned short* bp =
                    Wfrag + ((size_t)((nt*3 + nc)*16 + wl) << 9) + lane*8;
                #pragma unroll
                for (int g = 0; g < 3; ++g) bN[g] = *(const short8*)(bp + ((size_t)(g*4) << 9));
                if (nt == 4)
                    bOn = *(const short8*)(Wfrag + ((size_t)((4*3 + nc)*16 + 12 + wl) << 9) + lane*8);
            }
            if (tap == 4){
                acc[3][0] = __builtin_amdgcn_mfma_f32_16x16x32_bf16(aC[0], bO, acc[3][0], 0,0,0);
                acc[3][1] = __builtin_amdgcn_mfma_f32_16x16x32_bf16(aC[1], bO, acc[3][1], 0,0,0);
            }
            #pragma unroll
            for (int g = 0; g < 3; ++g){
                acc[g][0] = __builtin_amdgcn_mfma_f32_16x16x32_bf16(aC[0], bC[g], acc[g][0], 0,0,0);
                acc[g][1] = __builtin_amdgcn_mfma_f32_16x16x32_bf16(aC[1], bC[g], acc[g][1], 0,0,0);
            }
            if (have){
                aC[0]=aN[0]; aC[1]=aN[1];
                bC[0]=bN[0]; bC[1]=bN[1]; bC[2]=bN[2];
                if (nk % 9 == 4) bO = bOn;
            }
        }
    }

    // ---- combine halves through LDS (Xs is dead; P overlays it)
    __syncthreads();
    if (wh == 1){
        #pragma unroll
        for (int g = 0; g < 4; ++g)
            #pragma unroll
            for (int mf = 0; mf < 2; ++mf)
                *(f32x4*)(P + (size_t)(((wl*4 + g)*2 + mf)*256 + lane*4)) = acc[g][mf];
    }
    __syncthreads();
    if (wh == 0){
        #pragma unroll
        for (int g = 0; g < 4; ++g)
            #pragma unroll
            for (int mf = 0; mf < 2; ++mf)
                acc[g][mf] += *(const f32x4*)(P + (size_t)(((wl*4 + g)*2 + mf)*256 + lane*4));

        // ---- epilogue: wave-local gates; c in place, channel-last
        const int o = wl*16 + l15;
        #pragma unroll
        for (int mf = 0; mf < 2; ++mf){
            #pragma unroll
            for (int r = 0; r < 4; ++r){
                const int m = mf*16 + q*4 + r;
                const int pxg = x0 + m;
                const float fv = sigm_(acc[0][mf][r]);
                const float iv = sigm_(acc[1][mf][r]);
                const float gv = tanh_(acc[2][mf][r]);
                const float ov = sigm_(acc[3][mf][r]);
                const size_t cidx = (((size_t)(b*H_ + y)*W_ + pxg)*HID_ + o);
                const float cprev = t ? cbuf[cidx] : 0.0f;
                const float cn = cprev*fv + iv*gv;
                const float hn = tanh_(cn)*ov;
                if (t < T_-1){
                    cbuf[cidx] = cn;
                    hout[cidx] = f2bf(hn);
                } else {
                    const size_t oidx = ((((size_t)(b*HID_ + o))*H_ + y)*W_ + pxg);
                    out[oidx] = hn;
                    out[CSTRIDE_ + oidx] = cn;
                }
            }
        }
    }
}

extern "C" void kernel_launch(void* const* d_in, const int* in_sizes, int n_in,
                              void* d_out, int out_size, void* d_ws, size_t ws_size,
                              hipStream_t stream){
    const float* x  = (const float*)d_in[0];
    const float* Wf = (const float*)d_in[1];
    const float* bf = (const float*)d_in[2];
    const float* Wi = (const float*)d_in[3];
    const float* bi = (const float*)d_in[4];
    const float* Wc = (const float*)d_in[5];
    const float* bc = (const float*)d_in[6];
    const float* Wo = (const float*)d_in[7];
    const float* bo = (const float*)d_in[8];

    // ws: Wfrag 442368 | xbf 16777216 | cbuf 8388608 | hbfA 4194304 | hbfB 4194304
    unsigned short* Wfrag = (unsigned short*)d_ws;
    unsigned short* xbf   = (unsigned short*)((char*)d_ws + 442368);
    float*          cbuf  = (float*)((char*)d_ws + 442368 + 16777216);
    unsigned short* hbfA  = (unsigned short*)((char*)d_ws + 442368 + 16777216 + 8388608);
    unsigned short* hbfB  = hbfA + CSTRIDE_;

    prep_wfrag<<<dim3(864), dim3(256), 0, stream>>>(Wf, Wi, Wc, Wo, bf, bi, bc, bo, Wfrag);
    prep_xbf<<<dim3(2048), dim3(256), 0, stream>>>(x, xbf);

    for (int t = 0; t < T_; ++t){
        const unsigned short* hi = (t & 1) ? hbfA : hbfB;   // t==0 never reads
        unsigned short*       ho = (t & 1) ? hbfB : hbfA;
        lstm_step<<<dim3(1024), dim3(512), 0, stream>>>(
            xbf, Wfrag, cbuf, hi, ho, (float*)d_out, t);
    }
}